// Round 10
// baseline (407.797 us; speedup 1.0000x reference)
//
#include <hip/hip_runtime.h>
#include <hip/hip_cooperative_groups.h>
#include <cmath>

namespace cg = cooperative_groups;

#define D_IN 1024
#define D_OUT 1024
#define NUM_HEADS 16
#define HEAD_DIM 64
#define BATCH 2
#define SEQ 2048
#define GK 1024
#define KT 32
#define MAXGRID 768
#define OBS 72

typedef __attribute__((ext_vector_type(8))) short short8;
typedef __attribute__((ext_vector_type(4))) short short4v;
typedef __attribute__((ext_vector_type(4))) float float4v;

__device__ __forceinline__ unsigned short f2bf(float f) {
  unsigned int u = __builtin_bit_cast(unsigned int, f);
  unsigned int r = (u + 0x7FFFu + ((u >> 16) & 1u)) >> 16;
  return (unsigned short)r;
}
__device__ __forceinline__ float bf2f(unsigned short h) {
  return __builtin_bit_cast(float, (unsigned int)h << 16);
}

__device__ __forceinline__ void async_copy16(void* lds, const void* g) {
  __builtin_amdgcn_global_load_lds(
      (const __attribute__((address_space(1))) unsigned int*)g,
      (__attribute__((address_space(3))) unsigned int*)lds, 16, 0, 0);
}

#define DPP_F(x, ctrl) __builtin_bit_cast(float,                         \
    __builtin_amdgcn_update_dpp(__builtin_bit_cast(int, (x)),            \
                                __builtin_bit_cast(int, (x)),            \
                                (ctrl), 0xF, 0xF, false))

__device__ __forceinline__ float red16_sum(float x) {
  x += DPP_F(x, 0xB1);
  x += DPP_F(x, 0x4E);
  x += DPP_F(x, 0x124);
  x += DPP_F(x, 0x128);
  return x;
}

// ---------------------------------------------------------------------------
// Phase bodies (shared by fused cooperative kernel and fallback kernels).
// ---------------------------------------------------------------------------

// prep job 0..5119: z<4 transpose W tile; z==4 convert x chunk.
__device__ __forceinline__ void do_prep_job(
    int job, char* SM, const float* __restrict__ x, const float* __restrict__ Wq,
    const float* __restrict__ Wk, const float* __restrict__ Wv,
    const float* __restrict__ Wo, unsigned short* __restrict__ xb,
    unsigned short* __restrict__ wqkv_t, unsigned short* __restrict__ wo_t) {
  const int tid = threadIdx.x;
  const int z = job >> 10;
  const int t = job & 1023;
  if (z == 4) {
    const size_t i0 = ((size_t)t * 256 + tid) * 16;
#pragma unroll
    for (int half = 0; half < 2; ++half) {
      const size_t o = i0 + half * 8;
      float4 a = *(const float4*)(x + o);
      float4 b = *(const float4*)(x + o + 4);
      union { unsigned short u[8]; short8 v; } tt;
      tt.u[0] = f2bf(a.x); tt.u[1] = f2bf(a.y); tt.u[2] = f2bf(a.z); tt.u[3] = f2bf(a.w);
      tt.u[4] = f2bf(b.x); tt.u[5] = f2bf(b.y); tt.u[6] = f2bf(b.z); tt.u[7] = f2bf(b.w);
      *(short8*)(xb + o) = tt.v;
    }
    return;
  }
  const float* W = (z == 0) ? Wq : (z == 1) ? Wk : (z == 2) ? Wv : Wo;
  unsigned short* outp = (z < 3) ? (wqkv_t + (size_t)z * 1024 * 1024) : wo_t;
  float (*T)[33] = (float(*)[33])SM;
  const int r = tid >> 3;
  const int c4 = (tid & 7) << 2;
  const int k0 = (t & 31) * 32, n0 = (t >> 5) * 32;
  __syncthreads();  // previous job's T reads done
  float4 v = *(const float4*)(W + (size_t)(k0 + r) * 1024 + n0 + c4);
  T[r][c4 + 0] = v.x; T[r][c4 + 1] = v.y; T[r][c4 + 2] = v.z; T[r][c4 + 3] = v.w;
  __syncthreads();
  union { unsigned short u[4]; short4v v4; } o;
#pragma unroll
  for (int i = 0; i < 4; ++i) o.u[i] = f2bf(T[c4 + i][r]);
  *(short4v*)(outp + (size_t)(n0 + r) * 1024 + k0 + c4) = o.v4;
}

// bf16 MFMA GEMM core, BMI x 128 x 64 tile, XOR-swizzled LDS (0 conflicts).
template <int BMI>
__device__ __forceinline__ void gemm_core(
    const unsigned short* __restrict__ A, const unsigned short* __restrict__ Bt,
    unsigned short* As, unsigned short* Bs, int bm, int bn,
    float4v (&acc)[BMI / 32][4]) {
  constexpr int MI = BMI / 32;
  const int tid = threadIdx.x;
  const int wave = tid >> 6, lane = tid & 63;
  const int quad = lane >> 4, l16 = lane & 15;
  const int wr = wave >> 1, wc = wave & 1;
  const int sw = l16 & 7;

  int srowA[MI], sgcA[MI];
#pragma unroll
  for (int t = 0; t < MI; ++t) {
    const int c = (wave * MI + t) * 64 + lane;
    srowA[t] = c >> 3;
    sgcA[t] = ((c & 7) ^ (srowA[t] & 7)) * 8;
  }
  int srowB[4], sgcB[4];
#pragma unroll
  for (int t = 0; t < 4; ++t) {
    const int c = (wave * 4 + t) * 64 + lane;
    srowB[t] = c >> 3;
    sgcB[t] = ((c & 7) ^ (srowB[t] & 7)) * 8;
  }

  for (int k0 = 0; k0 < GK; k0 += 64) {
    __syncthreads();
#pragma unroll
    for (int t = 0; t < MI; ++t) {
      const int c = (wave * MI + t) * 64 + lane;
      async_copy16(As + (size_t)c * 8, A + (size_t)(bm + srowA[t]) * GK + k0 + sgcA[t]);
    }
#pragma unroll
    for (int t = 0; t < 4; ++t) {
      const int c = (wave * 4 + t) * 64 + lane;
      async_copy16(Bs + (size_t)c * 8, Bt + (size_t)(bn + srowB[t]) * GK + k0 + sgcB[t]);
    }
    __syncthreads();

#pragma unroll
    for (int h = 0; h < 2; ++h) {
      short8 af[MI], bf[4];
#pragma unroll
      for (int i = 0; i < MI; ++i) {
        const int row = wr * (BMI / 2) + i * 16 + l16;
        af[i] = *(const short8*)&As[((size_t)row * 8 + ((h * 4 + quad) ^ sw)) * 8];
      }
#pragma unroll
      for (int j = 0; j < 4; ++j) {
        const int row = wc * 64 + j * 16 + l16;
        bf[j] = *(const short8*)&Bs[((size_t)row * 8 + ((h * 4 + quad) ^ sw)) * 8];
      }
#pragma unroll
      for (int i = 0; i < MI; ++i)
#pragma unroll
        for (int j = 0; j < 4; ++j)
          acc[i][j] = __builtin_amdgcn_mfma_f32_16x16x32_bf16(af[i], bf[j], acc[i][j], 0, 0, 0);
    }
  }
}

// QKV tile 0..767.
__device__ __forceinline__ void do_qkv_tile(
    int tile, char* SM, const unsigned short* __restrict__ xb,
    const unsigned short* __restrict__ wqkv_t, const float* __restrict__ bq,
    const float* __restrict__ bk, const float* __restrict__ bv,
    unsigned short* __restrict__ qbuf, unsigned short* __restrict__ kblk,
    unsigned short* __restrict__ vblk) {
  unsigned short* As = (unsigned short*)SM;
  unsigned short* Bs = As + 8192;
  const int tid = threadIdx.x;
  const int wave = tid >> 6, lane = tid & 63;
  const int quad = lane >> 4, l16 = lane & 15;
  const int wr = wave >> 1, wc = wave & 1;
  const int bm = (tile & 31) * 128, bn = (tile >> 5) * 128;

  float4v acc[4][4] = {};
  gemm_core<128>(xb, wqkv_t, As, Bs, bm, bn, acc);

#pragma unroll
  for (int j = 0; j < 4; ++j) {
    const int n = bn + wc * 64 + j * 16 + l16;
    const int seg = n >> 10, nn = n & 1023;
    const int h = nn >> 6, d = nn & 63;
    const float bsv = (seg == 0) ? bq[nn] : (seg == 1) ? bk[nn] : bv[nn];
    const float scale = (seg == 0) ? 0.18033688011112043f : 1.0f;  // 0.125*log2e
#pragma unroll
    for (int i = 0; i < 4; ++i) {
#pragma unroll
      for (int r = 0; r < 4; ++r) {
        const int m = bm + wr * 64 + i * 16 + quad * 4 + r;
        const int b = m >> 11, s = m & 2047;
        const int bh = b * NUM_HEADS + h;
        const unsigned short hv = f2bf((acc[i][j][r] + bsv) * scale);
        if (seg == 0) {
          qbuf[((size_t)bh * SEQ + s) * HEAD_DIM + d] = hv;
        } else if (seg == 1) {
          kblk[((size_t)bh * 64 + (s >> 5)) * 2048 +
               (size_t)(((((s >> 4) & 1) * 2 + (d >> 5)) * 64 +
                         ((d >> 3) & 3) * 16 + (s & 15)) * 8 + (d & 7))] = hv;
        } else {
          vblk[((size_t)bh * 64 + (s >> 5)) * 2048 +
               (size_t)(((d >> 4) * 64 + ((s >> 3) & 3) * 16 + (d & 15)) * 8 +
                        (s & 7))] = hv;
        }
      }
    }
  }
}

// Attention job 0..2047: (bh, 32-row q-block), in-block split-K-4 (r7 body).
__device__ __forceinline__ void do_attn_job(
    int job, char* SM, const unsigned short* __restrict__ qbuf,
    const unsigned short* __restrict__ kblk, const unsigned short* __restrict__ vblk,
    unsigned short* __restrict__ cb) {
  unsigned short* PL = (unsigned short*)SM;     // 5120 shorts
  unsigned short* OB = PL + 5120;               // 9216 shorts
  float* LL = (float*)(SM + 28672);             // 128 floats

  const int tid = threadIdx.x;
  const int w = tid >> 6;
  const int lane = tid & 63;
  const int quad = lane >> 4;
  const int l16 = lane & 15;

  const int bh = job & 31;
  const int qblk = 63 - (job >> 5);  // long q-blocks first
  const int qw0 = qblk * 32;

  const int nt = qblk + 1;
  const int qch = (nt + 3) >> 2;
  const int t0 = w * qch;
  const int t1 = min(nt, t0 + qch);

  const size_t bh_base = (size_t)bh * SEQ * HEAD_DIM;
  const unsigned short* kb = kblk + bh_base;
  const unsigned short* vb = vblk + bh_base;
  unsigned short* PLw = PL + w * (32 * 40);

  short8 aq[2][2];
#pragma unroll
  for (int qt = 0; qt < 2; ++qt) {
    const unsigned short* qrow =
        qbuf + bh_base + (size_t)(qw0 + qt * 16 + l16) * HEAD_DIM + quad * 8;
    aq[qt][0] = *(const short8*)qrow;
    aq[qt][1] = *(const short8*)(qrow + 32);
  }

  float4v O[2][4] = {};
  float l_part[2][4] = {};

  if (t0 < t1) {
    short8 kA[4], vA[4], kB[4], vB[4];

    auto load = [&](int kt, short8 kd[4], short8 vd[4]) {
      const size_t base = (size_t)kt * 2048 + lane * 8;
#pragma unroll
      for (int f = 0; f < 4; ++f) kd[f] = *(const short8*)(kb + base + f * 512);
#pragma unroll
      for (int f = 0; f < 4; ++f) vd[f] = *(const short8*)(vb + base + f * 512);
    };

    auto step = [&](int kt, const short8 kd[4], const short8 vd[4], bool masked) {
      const int k0 = kt * KT;
      float4v cs[2][2];
#pragma unroll
      for (int qt = 0; qt < 2; ++qt)
#pragma unroll
        for (int g = 0; g < 2; ++g) {
          float4v c = {0.f, 0.f, 0.f, 0.f};
          c = __builtin_amdgcn_mfma_f32_16x16x32_bf16(aq[qt][0], kd[2 * g], c, 0, 0, 0);
          c = __builtin_amdgcn_mfma_f32_16x16x32_bf16(aq[qt][1], kd[2 * g + 1], c, 0, 0, 0);
          cs[qt][g] = c;
        }

#pragma unroll
      for (int qt = 0; qt < 2; ++qt)
#pragma unroll
        for (int g = 0; g < 2; ++g)
#pragma unroll
          for (int r = 0; r < 4; ++r) {
            float s = cs[qt][g][r];
            if (masked) {
              const int key = k0 + g * 16 + l16;
              const int qg = qw0 + qt * 16 + quad * 4 + r;
              s = (key <= qg) ? s : -1e30f;
            }
            const float p = __builtin_exp2f(s);
            l_part[qt][r] += p;
            const unsigned int pu = __builtin_bit_cast(unsigned int, p);
            PLw[(qt * 16 + quad * 4 + r) * 40 + (g * 2 + (l16 >> 3)) * 8 + (l16 & 7)] =
                (unsigned short)(pu >> 16);
          }

#pragma unroll
      for (int qt = 0; qt < 2; ++qt) {
        const short8 pA = *(const short8*)&PLw[(qt * 16 + l16) * 40 + quad * 8];
#pragma unroll
        for (int jj = 0; jj < 4; ++jj)
          O[qt][jj] = __builtin_amdgcn_mfma_f32_16x16x32_bf16(pA, vd[jj], O[qt][jj], 0, 0, 0);
      }
    };

    load(t0, kA, vA);
    int kt = t0;
    while (true) {
      const bool lastA = (kt == t1 - 1);
      if (!lastA) load(kt + 1, kB, vB);
      step(kt, kA, vA, kt == nt - 1);
      if (lastA) break;
      ++kt;
      const bool lastB = (kt == t1 - 1);
      if (!lastB) load(kt + 1, kA, vA);
      step(kt, kB, vB, kt == nt - 1);
      if (lastB) break;
      ++kt;
    }
  }

  // write this wave's partials to LDS
#pragma unroll
  for (int qt = 0; qt < 2; ++qt)
#pragma unroll
    for (int r = 0; r < 4; ++r) {
      const float lsum = red16_sum(l_part[qt][r]);
      const int row = qt * 16 + quad * 4 + r;
      if (l16 == 0) LL[w * 32 + row] = lsum;
#pragma unroll
      for (int jj = 0; jj < 4; ++jj)
        OB[(w * 32 + row) * OBS + jj * 16 + l16] = f2bf(O[qt][jj][r]);
    }

  __syncthreads();

  // in-LDS combine: wave w handles rows w*8..w*8+7
  const int row = w * 8 + (lane >> 3);
  const int col0 = (lane & 7) * 8;
  float acc[8] = {};
#pragma unroll
  for (int u = 0; u < 4; ++u) {
    const short8 t = *(const short8*)&OB[(u * 32 + row) * OBS + col0];
#pragma unroll
    for (int i = 0; i < 8; ++i) acc[i] += bf2f((unsigned short)t[i]);
  }
  const float inv = 1.0f / (LL[row] + LL[32 + row] + LL[64 + row] + LL[96 + row]);
  union { unsigned short u[8]; short8 v; } o;
#pragma unroll
  for (int i = 0; i < 8; ++i) o.u[i] = f2bf(acc[i] * inv);
  const int b = bh >> 4, h = bh & 15;
  const int qg = qw0 + row;
  *(short8*)(cb + ((size_t)b * SEQ + qg) * D_OUT + h * HEAD_DIM + col0) = o.v;
}

// Output tile 0..511: 64x128.
__device__ __forceinline__ void do_out_tile(
    int tile, char* SM, const unsigned short* __restrict__ cb,
    const unsigned short* __restrict__ wo_t, const float* __restrict__ bo,
    float* __restrict__ out) {
  unsigned short* As = (unsigned short*)SM;  // 4096 shorts
  unsigned short* Bs = As + 4096;            // 8192 shorts
  const int tid = threadIdx.x;
  const int wave = tid >> 6, lane = tid & 63;
  const int quad = lane >> 4, l16 = lane & 15;
  const int wr = wave >> 1, wc = wave & 1;
  const int bm = (tile & 63) * 64, bn = (tile >> 6) * 128;

  float4v acc[2][4] = {};
  gemm_core<64>(cb, wo_t, As, Bs, bm, bn, acc);

#pragma unroll
  for (int j = 0; j < 4; ++j) {
    const int n = bn + wc * 64 + j * 16 + l16;
    const float bsv = bo[n];
#pragma unroll
    for (int i = 0; i < 2; ++i) {
#pragma unroll
      for (int r = 0; r < 4; ++r) {
        const int m = bm + wr * 32 + i * 16 + quad * 4 + r;
        out[(size_t)m * D_OUT + n] = acc[i][j][r] + bsv;
      }
    }
  }
}

// ---------------------------------------------------------------------------
// Fused persistent cooperative kernel. Any grid size; phases 1-3 work-steal.
// ---------------------------------------------------------------------------
__global__ __launch_bounds__(256, 3) void fused(
    const float* __restrict__ x, const float* __restrict__ Wq,
    const float* __restrict__ Wk, const float* __restrict__ Wv,
    const float* __restrict__ Wo, const float* __restrict__ bq,
    const float* __restrict__ bk, const float* __restrict__ bv,
    const float* __restrict__ bo, unsigned short* __restrict__ xb,
    unsigned short* __restrict__ wqkv_t, unsigned short* __restrict__ wo_t,
    unsigned short* __restrict__ qbuf, unsigned short* __restrict__ kblk,
    unsigned short* __restrict__ vblk, unsigned short* __restrict__ cb,
    float* __restrict__ out, unsigned int* __restrict__ counters) {
  __shared__ __align__(16) char SM[32800];
  cg::grid_group grid = cg::this_grid();
  const int tid = threadIdx.x;
  int* jobshare = (int*)(SM + 32768);

  // Phase 0: prep (grid-stride; counters pre-zeroed by host memset)
  for (int job = blockIdx.x; job < 5120; job += gridDim.x)
    do_prep_job(job, SM, x, Wq, Wk, Wv, Wo, xb, wqkv_t, wo_t);

  grid.sync();

  // Phase 1: QKV GEMM, 768 tiles, work-stealing
  while (true) {
    __syncthreads();
    if (tid == 0) *jobshare = (int)atomicAdd(&counters[0], 1u);
    __syncthreads();
    const int tile = *jobshare;
    if (tile >= 768) break;
    do_qkv_tile(tile, SM, xb, wqkv_t, bq, bk, bv, qbuf, kblk, vblk);
  }

  grid.sync();

  // Phase 2: attention, 2048 jobs, work-stealing
  while (true) {
    __syncthreads();
    if (tid == 0) *jobshare = (int)atomicAdd(&counters[1], 1u);
    __syncthreads();
    const int job = *jobshare;
    if (job >= 2048) break;
    do_attn_job(job, SM, qbuf, kblk, vblk, cb);
  }

  grid.sync();

  // Phase 3: output GEMM, 512 tiles, work-stealing
  while (true) {
    __syncthreads();
    if (tid == 0) *jobshare = (int)atomicAdd(&counters[2], 1u);
    __syncthreads();
    const int tile = *jobshare;
    if (tile >= 512) break;
    do_out_tile(tile, SM, cb, wo_t, bo, out);
  }
}

// ---------------------------------------------------------------------------
// Fallback standalone kernels (r7 structure).
// ---------------------------------------------------------------------------
__global__ __launch_bounds__(256) void prep_k(
    const float* x, const float* Wq, const float* Wk, const float* Wv,
    const float* Wo, unsigned short* xb, unsigned short* wqkv_t,
    unsigned short* wo_t) {
  __shared__ __align__(16) char SM[4224];
  for (int job = blockIdx.x; job < 5120; job += gridDim.x)
    do_prep_job(job, SM, x, Wq, Wk, Wv, Wo, xb, wqkv_t, wo_t);
}

__global__ __launch_bounds__(256) void qkv_k(
    const unsigned short* xb, const unsigned short* wqkv_t, const float* bq,
    const float* bk, const float* bv, unsigned short* qbuf,
    unsigned short* kblk, unsigned short* vblk) {
  __shared__ __align__(16) char SM[32768];
  do_qkv_tile(blockIdx.x, SM, xb, wqkv_t, bq, bk, bv, qbuf, kblk, vblk);
}

__global__ __launch_bounds__(256) void attn_k(
    const unsigned short* qbuf, const unsigned short* kblk,
    const unsigned short* vblk, unsigned short* cb) {
  __shared__ __align__(16) char SM[29184];
  do_attn_job(blockIdx.x, SM, qbuf, kblk, vblk, cb);
}

__global__ __launch_bounds__(256) void out_k(
    const unsigned short* cb, const unsigned short* wo_t, const float* bo,
    float* out) {
  __shared__ __align__(16) char SM[24576];
  do_out_tile(blockIdx.x, SM, cb, wo_t, bo, out);
}

// ---------------------------------------------------------------------------
extern "C" void kernel_launch(void* const* d_in, const int* in_sizes, int n_in,
                              void* d_out, int out_size, void* d_ws, size_t ws_size,
                              hipStream_t stream) {
  const float* x  = (const float*)d_in[0];
  const float* Wq = (const float*)d_in[1];
  const float* bq = (const float*)d_in[2];
  const float* Wk = (const float*)d_in[3];
  const float* bk = (const float*)d_in[4];
  const float* Wv = (const float*)d_in[5];
  const float* bv = (const float*)d_in[6];
  const float* Wo = (const float*)d_in[7];
  const float* bo = (const float*)d_in[8];
  float* outp = (float*)d_out;

  const int M = BATCH * SEQ;  // 4096
  unsigned short* xb     = (unsigned short*)d_ws;                  // 8 MB
  unsigned short* wqkv_t = xb + (size_t)M * D_IN;                  // 6 MB
  unsigned short* wo_t   = wqkv_t + (size_t)3 * D_OUT * D_IN;      // 2 MB
  unsigned short* qb     = wo_t + (size_t)D_OUT * D_OUT;           // 8 MB
  unsigned short* kblk   = qb + (size_t)M * D_OUT;                 // 8 MB
  unsigned short* vblk   = kblk + (size_t)M * D_OUT;               // 8 MB
  unsigned short* cb     = vblk + (size_t)M * D_OUT;               // 8 MB
  unsigned int*   counters = (unsigned int*)(cb + (size_t)M * D_OUT);

  hipMemsetAsync(counters, 0, 16, stream);

  int maxPerCU = 0;
  hipError_t qerr = hipOccupancyMaxActiveBlocksPerMultiprocessor(
      &maxPerCU, fused, 256, 0);
  int grid = (qerr == hipSuccess) ? maxPerCU * 256 : 0;
  if (grid > MAXGRID) grid = MAXGRID;

  hipError_t err = hipErrorUnknown;
  if (grid >= 256) {
    void* args[] = {&x, &Wq, &Wk, &Wv, &Wo, &bq, &bk, &bv, &bo,
                    &xb, &wqkv_t, &wo_t, &qb, &kblk, &vblk, &cb, &outp, &counters};
    err = hipLaunchCooperativeKernel((const void*)fused, dim3(grid), dim3(256),
                                     args, 0, stream);
  }
  if (err != hipSuccess) {
    // fallback: proven 4-kernel path (r7)
    prep_k<<<768, 256, 0, stream>>>(x, Wq, Wk, Wv, Wo, xb, wqkv_t, wo_t);
    qkv_k<<<768, 256, 0, stream>>>(xb, wqkv_t, bq, bk, bv, qb, kblk, vblk);
    attn_k<<<2048, 256, 0, stream>>>(qb, kblk, vblk, cb);
    out_k<<<512, 256, 0, stream>>>(cb, wo_t, bo, outp);
  }
}

// Round 11
// 399.634 us; speedup vs baseline: 1.0204x; 1.0204x over previous
//
#include <hip/hip_runtime.h>
#include <hip/hip_cooperative_groups.h>
#include <cmath>

namespace cg = cooperative_groups;

#define D_IN 1024
#define D_OUT 1024
#define NUM_HEADS 16
#define HEAD_DIM 64
#define BATCH 2
#define SEQ 2048
#define GK 1024
#define KT 32
#define MAXGRID 768
#define OBS 72

typedef __attribute__((ext_vector_type(8))) short short8;
typedef __attribute__((ext_vector_type(4))) short short4v;
typedef __attribute__((ext_vector_type(4))) float float4v;

__device__ __forceinline__ unsigned short f2bf(float f) {
  unsigned int u = __builtin_bit_cast(unsigned int, f);
  unsigned int r = (u + 0x7FFFu + ((u >> 16) & 1u)) >> 16;
  return (unsigned short)r;
}
__device__ __forceinline__ float bf2f(unsigned short h) {
  return __builtin_bit_cast(float, (unsigned int)h << 16);
}

__device__ __forceinline__ void async_copy16(void* lds, const void* g) {
  __builtin_amdgcn_global_load_lds(
      (const __attribute__((address_space(1))) unsigned int*)g,
      (__attribute__((address_space(3))) unsigned int*)lds, 16, 0, 0);
}

#define DPP_F(x, ctrl) __builtin_bit_cast(float,                         \
    __builtin_amdgcn_update_dpp(__builtin_bit_cast(int, (x)),            \
                                __builtin_bit_cast(int, (x)),            \
                                (ctrl), 0xF, 0xF, false))

__device__ __forceinline__ float red16_sum(float x) {
  x += DPP_F(x, 0xB1);
  x += DPP_F(x, 0x4E);
  x += DPP_F(x, 0x124);
  x += DPP_F(x, 0x128);
  return x;
}

// ---------------------------------------------------------------------------
// Phase bodies (shared by fused cooperative kernel and fallback kernels).
// ---------------------------------------------------------------------------

// prep job 0..5119: z<4 transpose W tile; z==4 convert x chunk.
__device__ __forceinline__ void do_prep_job(
    int job, char* SM, const float* __restrict__ x, const float* __restrict__ Wq,
    const float* __restrict__ Wk, const float* __restrict__ Wv,
    const float* __restrict__ Wo, unsigned short* __restrict__ xb,
    unsigned short* __restrict__ wqkv_t, unsigned short* __restrict__ wo_t) {
  const int tid = threadIdx.x;
  const int z = job >> 10;
  const int t = job & 1023;
  if (z == 4) {
    const size_t i0 = ((size_t)t * 256 + tid) * 16;
#pragma unroll
    for (int half = 0; half < 2; ++half) {
      const size_t o = i0 + half * 8;
      float4 a = *(const float4*)(x + o);
      float4 b = *(const float4*)(x + o + 4);
      union { unsigned short u[8]; short8 v; } tt;
      tt.u[0] = f2bf(a.x); tt.u[1] = f2bf(a.y); tt.u[2] = f2bf(a.z); tt.u[3] = f2bf(a.w);
      tt.u[4] = f2bf(b.x); tt.u[5] = f2bf(b.y); tt.u[6] = f2bf(b.z); tt.u[7] = f2bf(b.w);
      *(short8*)(xb + o) = tt.v;
    }
    return;
  }
  const float* W = (z == 0) ? Wq : (z == 1) ? Wk : (z == 2) ? Wv : Wo;
  unsigned short* outp = (z < 3) ? (wqkv_t + (size_t)z * 1024 * 1024) : wo_t;
  float (*T)[33] = (float(*)[33])SM;
  const int r = tid >> 3;
  const int c4 = (tid & 7) << 2;
  const int k0 = (t & 31) * 32, n0 = (t >> 5) * 32;
  __syncthreads();  // previous job's T reads done
  float4 v = *(const float4*)(W + (size_t)(k0 + r) * 1024 + n0 + c4);
  T[r][c4 + 0] = v.x; T[r][c4 + 1] = v.y; T[r][c4 + 2] = v.z; T[r][c4 + 3] = v.w;
  __syncthreads();
  union { unsigned short u[4]; short4v v4; } o;
#pragma unroll
  for (int i = 0; i < 4; ++i) o.u[i] = f2bf(T[c4 + i][r]);
  *(short4v*)(outp + (size_t)(n0 + r) * 1024 + k0 + c4) = o.v4;
}

// bf16 MFMA GEMM core, BMI x 128 x 64 tile, XOR-swizzled LDS (0 conflicts).
template <int BMI>
__device__ __forceinline__ void gemm_core(
    const unsigned short* __restrict__ A, const unsigned short* __restrict__ Bt,
    unsigned short* As, unsigned short* Bs, int bm, int bn,
    float4v (&acc)[BMI / 32][4]) {
  constexpr int MI = BMI / 32;
  const int tid = threadIdx.x;
  const int wave = tid >> 6, lane = tid & 63;
  const int quad = lane >> 4, l16 = lane & 15;
  const int wr = wave >> 1, wc = wave & 1;
  const int sw = l16 & 7;

  int srowA[MI], sgcA[MI];
#pragma unroll
  for (int t = 0; t < MI; ++t) {
    const int c = (wave * MI + t) * 64 + lane;
    srowA[t] = c >> 3;
    sgcA[t] = ((c & 7) ^ (srowA[t] & 7)) * 8;
  }
  int srowB[4], sgcB[4];
#pragma unroll
  for (int t = 0; t < 4; ++t) {
    const int c = (wave * 4 + t) * 64 + lane;
    srowB[t] = c >> 3;
    sgcB[t] = ((c & 7) ^ (srowB[t] & 7)) * 8;
  }

  for (int k0 = 0; k0 < GK; k0 += 64) {
    __syncthreads();
#pragma unroll
    for (int t = 0; t < MI; ++t) {
      const int c = (wave * MI + t) * 64 + lane;
      async_copy16(As + (size_t)c * 8, A + (size_t)(bm + srowA[t]) * GK + k0 + sgcA[t]);
    }
#pragma unroll
    for (int t = 0; t < 4; ++t) {
      const int c = (wave * 4 + t) * 64 + lane;
      async_copy16(Bs + (size_t)c * 8, Bt + (size_t)(bn + srowB[t]) * GK + k0 + sgcB[t]);
    }
    __syncthreads();

#pragma unroll
    for (int h = 0; h < 2; ++h) {
      short8 af[MI], bf[4];
#pragma unroll
      for (int i = 0; i < MI; ++i) {
        const int row = wr * (BMI / 2) + i * 16 + l16;
        af[i] = *(const short8*)&As[((size_t)row * 8 + ((h * 4 + quad) ^ sw)) * 8];
      }
#pragma unroll
      for (int j = 0; j < 4; ++j) {
        const int row = wc * 64 + j * 16 + l16;
        bf[j] = *(const short8*)&Bs[((size_t)row * 8 + ((h * 4 + quad) ^ sw)) * 8];
      }
#pragma unroll
      for (int i = 0; i < MI; ++i)
#pragma unroll
        for (int j = 0; j < 4; ++j)
          acc[i][j] = __builtin_amdgcn_mfma_f32_16x16x32_bf16(af[i], bf[j], acc[i][j], 0, 0, 0);
    }
  }
}

// QKV tile 0..767.
__device__ __forceinline__ void do_qkv_tile(
    int tile, char* SM, const unsigned short* __restrict__ xb,
    const unsigned short* __restrict__ wqkv_t, const float* __restrict__ bq,
    const float* __restrict__ bk, const float* __restrict__ bv,
    unsigned short* __restrict__ qbuf, unsigned short* __restrict__ kblk,
    unsigned short* __restrict__ vblk) {
  unsigned short* As = (unsigned short*)SM;
  unsigned short* Bs = As + 8192;
  const int tid = threadIdx.x;
  const int wave = tid >> 6, lane = tid & 63;
  const int quad = lane >> 4, l16 = lane & 15;
  const int wr = wave >> 1, wc = wave & 1;
  const int bm = (tile & 31) * 128, bn = (tile >> 5) * 128;

  float4v acc[4][4] = {};
  gemm_core<128>(xb, wqkv_t, As, Bs, bm, bn, acc);

#pragma unroll
  for (int j = 0; j < 4; ++j) {
    const int n = bn + wc * 64 + j * 16 + l16;
    const int seg = n >> 10, nn = n & 1023;
    const int h = nn >> 6, d = nn & 63;
    const float bsv = (seg == 0) ? bq[nn] : (seg == 1) ? bk[nn] : bv[nn];
    const float scale = (seg == 0) ? 0.18033688011112043f : 1.0f;  // 0.125*log2e
#pragma unroll
    for (int i = 0; i < 4; ++i) {
#pragma unroll
      for (int r = 0; r < 4; ++r) {
        const int m = bm + wr * 64 + i * 16 + quad * 4 + r;
        const int b = m >> 11, s = m & 2047;
        const int bh = b * NUM_HEADS + h;
        const unsigned short hv = f2bf((acc[i][j][r] + bsv) * scale);
        if (seg == 0) {
          qbuf[((size_t)bh * SEQ + s) * HEAD_DIM + d] = hv;
        } else if (seg == 1) {
          kblk[((size_t)bh * 64 + (s >> 5)) * 2048 +
               (size_t)(((((s >> 4) & 1) * 2 + (d >> 5)) * 64 +
                         ((d >> 3) & 3) * 16 + (s & 15)) * 8 + (d & 7))] = hv;
        } else {
          vblk[((size_t)bh * 64 + (s >> 5)) * 2048 +
               (size_t)(((d >> 4) * 64 + ((s >> 3) & 3) * 16 + (d & 15)) * 8 +
                        (s & 7))] = hv;
        }
      }
    }
  }
}

// Attention job (bh, qblk): in-block split-K-4, in-LDS combine (r7 body).
__device__ __forceinline__ void do_attn_job(
    int bh, int qblk, char* SM, const unsigned short* __restrict__ qbuf,
    const unsigned short* __restrict__ kblk, const unsigned short* __restrict__ vblk,
    unsigned short* __restrict__ cb) {
  unsigned short* PL = (unsigned short*)SM;     // 5120 shorts
  unsigned short* OB = PL + 5120;               // 9216 shorts
  float* LL = (float*)(SM + 28672);             // 128 floats

  const int tid = threadIdx.x;
  const int w = tid >> 6;
  const int lane = tid & 63;
  const int quad = lane >> 4;
  const int l16 = lane & 15;

  const int qw0 = qblk * 32;
  const int nt = qblk + 1;
  const int qch = (nt + 3) >> 2;
  const int t0 = w * qch;
  const int t1 = min(nt, t0 + qch);

  const size_t bh_base = (size_t)bh * SEQ * HEAD_DIM;
  const unsigned short* kb = kblk + bh_base;
  const unsigned short* vb = vblk + bh_base;
  unsigned short* PLw = PL + w * (32 * 40);

  short8 aq[2][2];
#pragma unroll
  for (int qt = 0; qt < 2; ++qt) {
    const unsigned short* qrow =
        qbuf + bh_base + (size_t)(qw0 + qt * 16 + l16) * HEAD_DIM + quad * 8;
    aq[qt][0] = *(const short8*)qrow;
    aq[qt][1] = *(const short8*)(qrow + 32);
  }

  float4v O[2][4] = {};
  float l_part[2][4] = {};

  if (t0 < t1) {
    short8 kA[4], vA[4], kB[4], vB[4];

    auto load = [&](int kt, short8 kd[4], short8 vd[4]) {
      const size_t base = (size_t)kt * 2048 + lane * 8;
#pragma unroll
      for (int f = 0; f < 4; ++f) kd[f] = *(const short8*)(kb + base + f * 512);
#pragma unroll
      for (int f = 0; f < 4; ++f) vd[f] = *(const short8*)(vb + base + f * 512);
    };

    auto step = [&](int kt, const short8 kd[4], const short8 vd[4], bool masked) {
      const int k0 = kt * KT;
      float4v cs[2][2];
#pragma unroll
      for (int qt = 0; qt < 2; ++qt)
#pragma unroll
        for (int g = 0; g < 2; ++g) {
          float4v c = {0.f, 0.f, 0.f, 0.f};
          c = __builtin_amdgcn_mfma_f32_16x16x32_bf16(aq[qt][0], kd[2 * g], c, 0, 0, 0);
          c = __builtin_amdgcn_mfma_f32_16x16x32_bf16(aq[qt][1], kd[2 * g + 1], c, 0, 0, 0);
          cs[qt][g] = c;
        }

#pragma unroll
      for (int qt = 0; qt < 2; ++qt)
#pragma unroll
        for (int g = 0; g < 2; ++g)
#pragma unroll
          for (int r = 0; r < 4; ++r) {
            float s = cs[qt][g][r];
            if (masked) {
              const int key = k0 + g * 16 + l16;
              const int qg = qw0 + qt * 16 + quad * 4 + r;
              s = (key <= qg) ? s : -1e30f;
            }
            const float p = __builtin_exp2f(s);
            l_part[qt][r] += p;
            const unsigned int pu = __builtin_bit_cast(unsigned int, p);
            PLw[(qt * 16 + quad * 4 + r) * 40 + (g * 2 + (l16 >> 3)) * 8 + (l16 & 7)] =
                (unsigned short)(pu >> 16);
          }

#pragma unroll
      for (int qt = 0; qt < 2; ++qt) {
        const short8 pA = *(const short8*)&PLw[(qt * 16 + l16) * 40 + quad * 8];
#pragma unroll
        for (int jj = 0; jj < 4; ++jj)
          O[qt][jj] = __builtin_amdgcn_mfma_f32_16x16x32_bf16(pA, vd[jj], O[qt][jj], 0, 0, 0);
      }
    };

    load(t0, kA, vA);
    int kt = t0;
    while (true) {
      const bool lastA = (kt == t1 - 1);
      if (!lastA) load(kt + 1, kB, vB);
      step(kt, kA, vA, kt == nt - 1);
      if (lastA) break;
      ++kt;
      const bool lastB = (kt == t1 - 1);
      if (!lastB) load(kt + 1, kA, vA);
      step(kt, kB, vB, kt == nt - 1);
      if (lastB) break;
      ++kt;
    }
  }

  // write this wave's partials to LDS
#pragma unroll
  for (int qt = 0; qt < 2; ++qt)
#pragma unroll
    for (int r = 0; r < 4; ++r) {
      const float lsum = red16_sum(l_part[qt][r]);
      const int row = qt * 16 + quad * 4 + r;
      if (l16 == 0) LL[w * 32 + row] = lsum;
#pragma unroll
      for (int jj = 0; jj < 4; ++jj)
        OB[(w * 32 + row) * OBS + jj * 16 + l16] = f2bf(O[qt][jj][r]);
    }

  __syncthreads();

  // in-LDS combine: wave w handles rows w*8..w*8+7
  const int row = w * 8 + (lane >> 3);
  const int col0 = (lane & 7) * 8;
  float acc[8] = {};
#pragma unroll
  for (int u = 0; u < 4; ++u) {
    const short8 t = *(const short8*)&OB[(u * 32 + row) * OBS + col0];
#pragma unroll
    for (int i = 0; i < 8; ++i) acc[i] += bf2f((unsigned short)t[i]);
  }
  const float inv = 1.0f / (LL[row] + LL[32 + row] + LL[64 + row] + LL[96 + row]);
  union { unsigned short u[8]; short8 v; } o;
#pragma unroll
  for (int i = 0; i < 8; ++i) o.u[i] = f2bf(acc[i] * inv);
  const int b = bh >> 4, h = bh & 15;
  const int qg = qw0 + row;
  *(short8*)(cb + ((size_t)b * SEQ + qg) * D_OUT + h * HEAD_DIM + col0) = o.v;
}

// Output tile 0..511: 64x128.
__device__ __forceinline__ void do_out_tile(
    int tile, char* SM, const unsigned short* __restrict__ cb,
    const unsigned short* __restrict__ wo_t, const float* __restrict__ bo,
    float* __restrict__ out) {
  unsigned short* As = (unsigned short*)SM;  // 4096 shorts
  unsigned short* Bs = As + 4096;            // 8192 shorts
  const int tid = threadIdx.x;
  const int wave = tid >> 6, lane = tid & 63;
  const int quad = lane >> 4, l16 = lane & 15;
  const int wr = wave >> 1, wc = wave & 1;
  const int bm = (tile & 63) * 64, bn = (tile >> 6) * 128;

  float4v acc[2][4] = {};
  gemm_core<64>(cb, wo_t, As, Bs, bm, bn, acc);

#pragma unroll
  for (int j = 0; j < 4; ++j) {
    const int n = bn + wc * 64 + j * 16 + l16;
    const float bsv = bo[n];
#pragma unroll
    for (int i = 0; i < 2; ++i) {
#pragma unroll
      for (int r = 0; r < 4; ++r) {
        const int m = bm + wr * 32 + i * 16 + quad * 4 + r;
        out[(size_t)m * D_OUT + n] = acc[i][j][r] + bsv;
      }
    }
  }
}

// ---------------------------------------------------------------------------
// Fused persistent cooperative kernel with PER-XCD work-stealing:
// block group x = blockIdx&7 steals only jobs ≡ x (mod 8), preserving the
// XCD L2 locality the split-kernel path had (r10's global steal thrashed L2:
// FETCH 290 MB vs 90). counters[0..7]=qkv, [8..15]=attn, [16..23]=out.
// ---------------------------------------------------------------------------
__global__ __launch_bounds__(256, 3) void fused(
    const float* __restrict__ x, const float* __restrict__ Wq,
    const float* __restrict__ Wk, const float* __restrict__ Wv,
    const float* __restrict__ Wo, const float* __restrict__ bq,
    const float* __restrict__ bk, const float* __restrict__ bv,
    const float* __restrict__ bo, unsigned short* __restrict__ xb,
    unsigned short* __restrict__ wqkv_t, unsigned short* __restrict__ wo_t,
    unsigned short* __restrict__ qbuf, unsigned short* __restrict__ kblk,
    unsigned short* __restrict__ vblk, unsigned short* __restrict__ cb,
    float* __restrict__ out, unsigned int* __restrict__ counters) {
  __shared__ __align__(16) char SM[32800];
  cg::grid_group grid = cg::this_grid();
  const int tid = threadIdx.x;
  const int xcd = blockIdx.x & 7;
  int* jobshare = (int*)(SM + 32768);

  // Phase 0: prep (grid-stride)
  for (int job = blockIdx.x; job < 5120; job += gridDim.x)
    do_prep_job(job, SM, x, Wq, Wk, Wv, Wo, xb, wqkv_t, wo_t);

  grid.sync();

  // Phase 1: QKV GEMM — 96 tiles per XCD group (tile = j*8+xcd)
  while (true) {
    __syncthreads();
    if (tid == 0) *jobshare = (int)atomicAdd(&counters[xcd], 1u);
    __syncthreads();
    const int j = *jobshare;
    if (j >= 96) break;
    do_qkv_tile(j * 8 + xcd, SM, xb, wqkv_t, bq, bk, bv, qbuf, kblk, vblk);
  }

  grid.sync();

  // Phase 2: attention — 256 jobs per XCD group: bh = xcd+8*(j&3) (4 bh's
  // per XCD -> 2 MB K/V, L2-resident), long q-blocks first.
  while (true) {
    __syncthreads();
    if (tid == 0) *jobshare = (int)atomicAdd(&counters[8 + xcd], 1u);
    __syncthreads();
    const int j = *jobshare;
    if (j >= 256) break;
    do_attn_job(xcd + 8 * (j & 3), 63 - (j >> 2), SM, qbuf, kblk, vblk, cb);
  }

  grid.sync();

  // Phase 3: output GEMM — 64 tiles per XCD group (tile = j*8+xcd)
  while (true) {
    __syncthreads();
    if (tid == 0) *jobshare = (int)atomicAdd(&counters[16 + xcd], 1u);
    __syncthreads();
    const int j = *jobshare;
    if (j >= 64) break;
    do_out_tile(j * 8 + xcd, SM, cb, wo_t, bo, out);
  }
}

// ---------------------------------------------------------------------------
// Fallback standalone kernels (r7 structure).
// ---------------------------------------------------------------------------
__global__ __launch_bounds__(256) void prep_k(
    const float* x, const float* Wq, const float* Wk, const float* Wv,
    const float* Wo, unsigned short* xb, unsigned short* wqkv_t,
    unsigned short* wo_t) {
  __shared__ __align__(16) char SM[4224];
  for (int job = blockIdx.x; job < 5120; job += gridDim.x)
    do_prep_job(job, SM, x, Wq, Wk, Wv, Wo, xb, wqkv_t, wo_t);
}

__global__ __launch_bounds__(256) void qkv_k(
    const unsigned short* xb, const unsigned short* wqkv_t, const float* bq,
    const float* bk, const float* bv, unsigned short* qbuf,
    unsigned short* kblk, unsigned short* vblk) {
  __shared__ __align__(16) char SM[32768];
  do_qkv_tile(blockIdx.x, SM, xb, wqkv_t, bq, bk, bv, qbuf, kblk, vblk);
}

__global__ __launch_bounds__(256) void attn_k(
    const unsigned short* qbuf, const unsigned short* kblk,
    const unsigned short* vblk, unsigned short* cb) {
  __shared__ __align__(16) char SM[29184];
  const int job = blockIdx.x;
  do_attn_job(job & 31, 63 - (job >> 5), SM, qbuf, kblk, vblk, cb);
}

__global__ __launch_bounds__(256) void out_k(
    const unsigned short* cb, const unsigned short* wo_t, const float* bo,
    float* out) {
  __shared__ __align__(16) char SM[24576];
  do_out_tile(blockIdx.x, SM, cb, wo_t, bo, out);
}

// ---------------------------------------------------------------------------
extern "C" void kernel_launch(void* const* d_in, const int* in_sizes, int n_in,
                              void* d_out, int out_size, void* d_ws, size_t ws_size,
                              hipStream_t stream) {
  const float* x  = (const float*)d_in[0];
  const float* Wq = (const float*)d_in[1];
  const float* bq = (const float*)d_in[2];
  const float* Wk = (const float*)d_in[3];
  const float* bk = (const float*)d_in[4];
  const float* Wv = (const float*)d_in[5];
  const float* bv = (const float*)d_in[6];
  const float* Wo = (const float*)d_in[7];
  const float* bo = (const float*)d_in[8];
  float* outp = (float*)d_out;

  const int M = BATCH * SEQ;  // 4096
  unsigned short* xb     = (unsigned short*)d_ws;                  // 8 MB
  unsigned short* wqkv_t = xb + (size_t)M * D_IN;                  // 6 MB
  unsigned short* wo_t   = wqkv_t + (size_t)3 * D_OUT * D_IN;      // 2 MB
  unsigned short* qb     = wo_t + (size_t)D_OUT * D_OUT;           // 8 MB
  unsigned short* kblk   = qb + (size_t)M * D_OUT;                 // 8 MB
  unsigned short* vblk   = kblk + (size_t)M * D_OUT;               // 8 MB
  unsigned short* cb     = vblk + (size_t)M * D_OUT;               // 8 MB
  unsigned int*   counters = (unsigned int*)(cb + (size_t)M * D_OUT);

  hipMemsetAsync(counters, 0, 128, stream);

  int maxPerCU = 0;
  hipError_t qerr = hipOccupancyMaxActiveBlocksPerMultiprocessor(
      &maxPerCU, fused, 256, 0);
  int grid = (qerr == hipSuccess) ? maxPerCU * 256 : 0;
  if (grid > MAXGRID) grid = MAXGRID;

  hipError_t err = hipErrorUnknown;
  if (grid >= 256) {
    void* args[] = {&x, &Wq, &Wk, &Wv, &Wo, &bq, &bk, &bv, &bo,
                    &xb, &wqkv_t, &wo_t, &qb, &kblk, &vblk, &cb, &outp, &counters};
    err = hipLaunchCooperativeKernel((const void*)fused, dim3(grid), dim3(256),
                                     args, 0, stream);
  }
  if (err != hipSuccess) {
    // fallback: proven 4-kernel path (r7)
    prep_k<<<768, 256, 0, stream>>>(x, Wq, Wk, Wv, Wo, xb, wqkv_t, wo_t);
    qkv_k<<<768, 256, 0, stream>>>(xb, wqkv_t, bq, bk, bv, qb, kblk, vblk);
    attn_k<<<2048, 256, 0, stream>>>(qb, kblk, vblk, cb);
    out_k<<<512, 256, 0, stream>>>(cb, wo_t, bo, outp);
  }
}